// Round 5
// baseline (210.865 us; speedup 1.0000x reference)
//
#include <hip/hip_runtime.h>

#define B_ 8
#define C_ 256
#define HW_ 4096
#define E_ 32
#define K_ 8192
#define N_ 32768          // B*H*W
#define NCHUNK 4
#define KC_ (K_ / NCHUNK) // 2048
#define NSTAGE (KC_ / 128)   // 16
#define KSEG 32              // codes per k_dwfinal block
#define PIX 128              // pixels per k_score block

#define DECAY_ 0.99f
#define OMD_   0.01f
#define EPS_   1e-5f
#define BETA_  0.25f

// ---- output layout (fp32 elements, concatenated in reference return order) ----
#define O_ZQ   0          // [B,E,H,W] 1048576
#define O_IDX  1048576    // [B,H,W]   32768
#define O_QL   1081344    // scalar    1
#define O_NEMB 1081345    // [K,E]     262144
#define O_NCS  1343489    // [K]       8192
#define O_NW   1351681    // [K,E]     262144

// ---- workspace layout (float offsets); high-water 1573504 floats = 6.3 MB ----
// eh/em PRE-SWIZZLED to MFMA-frag order: uint4 chunk (tile t, quad q, c15) at t*64+q*16+c15.
#define WS_EH   0u        // K*E bf16 hi   [0,       131072)
#define WS_EM   131072u   // K*E bf16 lo   [131072,  262144)
#define WS_Z    262144u   // N*E fp32 z    [262144, 1310720)
#define WS_PACK 1310720u  // 4 chunks x N int2 (top1,top2) [1310720, 1572864)
#define WS_PCS  1572864u  // 128 per-block partial sums of cs_in
#define WS_QP   1572992u  // 512 per-block qloss partials
// NO memset needed: every ws word consumed is written first by a prior kernel.

typedef float f32x4 __attribute__((ext_vector_type(4)));
typedef short s16x8 __attribute__((ext_vector_type(8)));
typedef unsigned long long u64;

__device__ __forceinline__ unsigned short f2bf(float f) {
    unsigned u = __float_as_uint(f);
    u = u + 0x7fffu + ((u >> 16) & 1u);
    return (unsigned short)(u >> 16);
}
__device__ __forceinline__ float bf2f(unsigned short h) {
    return __uint_as_float(((unsigned)h) << 16);
}
__device__ __forceinline__ unsigned ford(float f) {
    unsigned u = __float_as_uint(f);
    return (u & 0x80000000u) ? ~u : (u | 0x80000000u);
}
__device__ __forceinline__ int imax(int a, int b) { return a > b ? a : b; }
__device__ __forceinline__ int imin(int a, int b) { return a < b ? a : b; }

__device__ __forceinline__ void gload_lds16(const void* g, void* l) {
    __builtin_amdgcn_global_load_lds(
        (const __attribute__((address_space(1))) unsigned int*)g,
        (__attribute__((address_space(3))) unsigned int*)l, 16, 0, 0);
}

// ---------------- K0: fused {norm_split + cs-partials} || {z = x@WqT + bq} ----------------
// blocks [0,128): codebook normalize/split (4 thr/row) + per-block sum(cs_in) partial.
// blocks [128,640): z for 64 pixels each; 8 e's per thread (4 e-groups).
__global__ __launch_bounds__(256) void k_pre(const float* __restrict__ emb,
                                             const float* __restrict__ cs,
                                             uint4* __restrict__ eh16,
                                             uint4* __restrict__ em16,
                                             float* __restrict__ part_cs,
                                             const float* __restrict__ x,
                                             const float* __restrict__ Wq,
                                             const float* __restrict__ bq,
                                             float* __restrict__ zout) {
    __shared__ float wqt[C_ * E_];   // 32 KB, used by z branch only
    int tid = threadIdx.x;

    if (blockIdx.x < 128) {
        // ---- norm_split branch ----
        int t4 = blockIdx.x * 256 + tid;           // 0..32767
        int k = t4 >> 2, q = t4 & 3;               // row, quad (8 elements)
        const float4* r = (const float4*)(emb + (size_t)k * E_ + q * 8);
        float4 u0 = r[0], u1 = r[1];
        float ss = u0.x*u0.x + u0.y*u0.y + u0.z*u0.z + u0.w*u0.w
                 + u1.x*u1.x + u1.y*u1.y + u1.z*u1.z + u1.w*u1.w;
        ss += __shfl_xor(ss, 1, 64);
        ss += __shfl_xor(ss, 2, 64);               // full-row ||.||^2 in all 4 lanes
        float inv = 1.0f / fmaxf(sqrtf(ss), 1e-12f);

        float v[8] = {u0.x, u0.y, u0.z, u0.w, u1.x, u1.y, u1.z, u1.w};
        unsigned short h1a[8], h2a[8];
#pragma unroll
        for (int e = 0; e < 8; e++) {
            float en = v[e] * inv;
            unsigned short h1 = f2bf(en);
            float r1 = en - bf2f(h1);
            h1a[e] = h1; h2a[e] = f2bf(r1);
        }
        int t = k >> 4, c15 = k & 15;
        eh16[t * 64 + q * 16 + c15] = ((uint4*)h1a)[0];
        em16[t * 64 + q * 16 + c15] = ((uint4*)h2a)[0];

        // per-block partial of sum(cs_in): rows [blockIdx*64, +64)
        if (tid < 64) {
            float cv = cs[blockIdx.x * 64 + tid];
#pragma unroll
            for (int off = 32; off > 0; off >>= 1) cv += __shfl_down(cv, off);
            if (tid == 0) part_cs[blockIdx.x] = cv;
        }
        return;
    }

    // ---- z branch: 64 pixels, eg = tid>>6 owns 8 e's ----
    int zb = blockIdx.x - 128;
#pragma unroll
    for (int i = 0; i < 32; i++) {
        int g = i * 256 + tid;        // g = e*256 + c  (Wq is [E,C])
        int e = g >> 8;
        int c = g & 255;
        wqt[c * E_ + e] = Wq[g];
    }
    __syncthreads();
    int lp = tid & 63, eg = tid >> 6;
    int n0 = zb * 64 + lp;
    int b  = n0 >> 12, hw = n0 & (HW_ - 1);
    const float* xp = x + (size_t)b * C_ * HW_ + hw;
    float a[8];
#pragma unroll
    for (int j = 0; j < 8; j++) a[j] = 0.f;
#pragma unroll 4
    for (int c = 0; c < C_; c++) {
        float xv = xp[(size_t)c * HW_];
        const float4* wr = (const float4*)(wqt + c * E_ + eg * 8);
        float4 w0 = wr[0], w1 = wr[1];
        a[0] += xv * w0.x; a[1] += xv * w0.y; a[2] += xv * w0.z; a[3] += xv * w0.w;
        a[4] += xv * w1.x; a[5] += xv * w1.y; a[6] += xv * w1.z; a[7] += xv * w1.w;
    }
    float4 o0 = make_float4(a[0] + bq[eg*8+0], a[1] + bq[eg*8+1],
                            a[2] + bq[eg*8+2], a[3] + bq[eg*8+3]);
    float4 o1 = make_float4(a[4] + bq[eg*8+4], a[5] + bq[eg*8+5],
                            a[6] + bq[eg*8+6], a[7] + bq[eg*8+7]);
    float4* zg = (float4*)(zout + (size_t)n0 * E_ + eg * 8);
    zg[0] = o0; zg[1] = o1;
}

// ---------------- K1: MFMA score + int-packed per-pixel chunk-local top-2 ----------------
// grid (N/128, NCHUNK), 512 thr (8 waves), 128 pixels, quarter codebook per block.
// NO min-waves clause: round-3 showed __launch_bounds__(512,8) squeezes VGPR 44->32
// and spills to scratch (WRITE_SIZE 1MB->303MB). Plain (512) keeps 44 VGPR; 4 blocks/CU
// x 8 waves = 32 waves/CU occupancy cap with the same 32 KB LDS.
// LDS: [0,16384) buf0, [16384,32768) buf1 (stage: 8KB hi + 8KB lo).
__global__ __launch_bounds__(512) void k_score_mfma(const float* __restrict__ zws,
                                                    const char* __restrict__ ehb,
                                                    const char* __restrict__ emb_b,
                                                    int2* __restrict__ pk2) {
    __shared__ __align__(16) char smem[32768];

    int tid  = threadIdx.x;
    int lane = tid & 63;
    int w    = tid >> 6;          // 0..7
    int chunk = blockIdx.y;

    // ---- A fragments from cached z: z * 2^27 (exact), 2-way bf16 split.
    //      A[m=lane&15][k=(lane>>4)*8+j] ----
    s16x8 a1, a2;
    {
        int ploc = w * 16 + (lane & 15);          // 0..127
        int n0   = blockIdx.x * PIX + ploc;
        int e0   = (lane >> 4) * 8;
        const float4* zp = (const float4*)(zws + (size_t)n0 * E_ + e0);
        float4 z0 = zp[0], z1 = zp[1];
        float zz[8] = {z0.x, z0.y, z0.z, z0.w, z1.x, z1.y, z1.z, z1.w};
#pragma unroll
        for (int j = 0; j < 8; j++) {
            float zv = zz[j] * 134217728.0f;  // 2^27
            unsigned short h1 = f2bf(zv);
            float r1 = zv - bf2f(h1);
            a1[j] = (short)h1; a2[j] = (short)f2bf(r1);
        }
    }

    // staging sources (pre-swizzled planes are stage-linear); 512 thr x 2 = 1024 chunks
    const char* srcp[2];
#pragma unroll
    for (int i = 0; i < 2; i++) {
        int d = i * 512 + tid;
        int pl = d >> 9, dd = d & 511;
        srcp[i] = (pl ? emb_b : ehb) + (size_t)chunk * (KC_ * 64) + dd * 16;
    }

    // prologue: stage 0 -> buf0
#pragma unroll
    for (int i = 0; i < 2; i++)
        gload_lds16(srcp[i], smem + (i * 512 + tid) * 16);
    __syncthreads();

    int rbase = 8191 - chunk * KC_ - (lane & 15);
    int bq1[4], bq2[4];
#pragma unroll
    for (int j = 0; j < 4; j++) { bq1[j] = (int)0x80000000; bq2[j] = (int)0x80000000; }
    f32x4 zero4 = {0.f, 0.f, 0.f, 0.f};

    for (int st = 0; st < NSTAGE; st++) {
        if (st + 1 < NSTAGE) {
            char* dst = smem + ((st + 1) & 1) * 16384;
#pragma unroll
            for (int i = 0; i < 2; i++)
                gload_lds16(srcp[i] + (size_t)(st + 1) * 8192, dst + (i * 512 + tid) * 16);
        }
        const char* cur = smem + (st & 1) * 16384;
        int rst = rbase - st * 128;

#pragma unroll
        for (int g = 0; g < 2; g++) {
            int ct = g * 4;
            s16x8 b1[4], b2[4];
#pragma unroll
            for (int q = 0; q < 4; q++) {
                b1[q] = ((const s16x8*)(cur +        (ct + q) * 1024))[lane];
                b2[q] = ((const s16x8*)(cur + 8192 + (ct + q) * 1024))[lane];
            }
            f32x4 acc[4];
#pragma unroll
            for (int q = 0; q < 4; q++)
                acc[q] = __builtin_amdgcn_mfma_f32_16x16x32_bf16(a1, b1[q], zero4, 0, 0, 0);
#pragma unroll
            for (int q = 0; q < 4; q++)
                acc[q] = __builtin_amdgcn_mfma_f32_16x16x32_bf16(a1, b2[q], acc[q], 0, 0, 0);
#pragma unroll
            for (int q = 0; q < 4; q++)
                acc[q] = __builtin_amdgcn_mfma_f32_16x16x32_bf16(a2, b1[q], acc[q], 0, 0, 0);
            int r0 = rst - ct * 16;
            // tournament over 4 tiles; only the group winner enters the running top-2.
            // (safe: a dropped group loser matters only on a packed-key quantization
            //  tie — P ~ 1e-4/run — and the exact rescore of 8 candidates covers ties.)
#pragma unroll
            for (int j = 0; j < 4; j++) {
                int v0 = ((int)acc[0][j] & (int)0xFFFFE000) | r0;
                int v1 = ((int)acc[1][j] & (int)0xFFFFE000) | (r0 - 16);
                int v2 = ((int)acc[2][j] & (int)0xFFFFE000) | (r0 - 32);
                int v3 = ((int)acc[3][j] & (int)0xFFFFE000) | (r0 - 48);
                int hi = imax(imax(v0, v1), imax(v2, v3));
                int m  = imin(bq1[j], hi);
                bq1[j] = imax(bq1[j], hi);
                bq2[j] = imax(bq2[j], m);
            }
        }
        __syncthreads();
    }

    // butterfly top-2 merge across 16-lane code groups
#pragma unroll
    for (int off = 1; off < 16; off <<= 1) {
#pragma unroll
        for (int j = 0; j < 4; j++) {
            int o1 = __shfl_xor(bq1[j], off, 64);
            int o2 = __shfl_xor(bq2[j], off, 64);
            int m  = imin(bq1[j], o1);
            bq1[j] = imax(bq1[j], o1);
            bq2[j] = imax(imax(bq2[j], o2), m);
        }
    }
    if ((lane & 15) == 0) {
        int rowbase = blockIdx.x * PIX + w * 16 + (lane >> 4) * 4;
#pragma unroll
        for (int j = 0; j < 4; j++)
            pk2[(size_t)chunk * N_ + rowbase + j] = make_int2(bq1[j], bq2[j]);
    }
}

// exact rescore of one candidate code against z[32]
__device__ __forceinline__ float rescore(const float* __restrict__ emb, int k,
                                         const float* zrow) {
    const float4* r = (const float4*)(emb + (size_t)k * E_);
    float4 v[8];
    float ss = 0.f;
#pragma unroll
    for (int i = 0; i < 8; i++) {
        v[i] = r[i];
        ss += v[i].x * v[i].x + v[i].y * v[i].y + v[i].z * v[i].z + v[i].w * v[i].w;
    }
    float inv = 1.0f / fmaxf(sqrtf(ss), 1e-12f);
    const float4* zp = (const float4*)zrow;
    float sx = 0.f, sy = 0.f, sz = 0.f, sw = 0.f;
#pragma unroll
    for (int i = 0; i < 8; i++) {
        float4 e4 = make_float4(v[i].x * inv, v[i].y * inv, v[i].z * inv, v[i].w * inv);
        float4 zr = zp[i];
        sx += zr.x * e4.x; sy += zr.y * e4.y;
        sz += zr.z * e4.z; sw += zr.w * e4.w;
    }
    return (sx + sy) + (sz + sw);
}

// ---------------- K2: load cached z, rescore 8 candidates, gather + zq/idx/qloss-partial ----------------
// 256 threads, 64 pixels. 4 threads/pixel, each rescores its chunk's (top1, top2).
__global__ __launch_bounds__(256) void k_scatter(const float* __restrict__ zws,
                                                 const int2* __restrict__ pk2,
                                                 const float* __restrict__ emb,
                                                 float* __restrict__ out_zq,
                                                 float* __restrict__ out_idx,
                                                 float* __restrict__ qpart) {
    __shared__ float zbuf[64 * E_];    // 8 KB
    __shared__ int   idxs_s[64];
    __shared__ float red[4];
    int tid = threadIdx.x;

    // coalesced z load: 2048 floats = 512 float4
    const float4* zsrc = (const float4*)(zws + (size_t)blockIdx.x * 64 * E_);
    float4* zdst = (float4*)zbuf;
    zdst[tid]       = zsrc[tid];
    zdst[tid + 256] = zsrc[tid + 256];
    __syncthreads();

    {   // 8 candidates per pixel: (chunk 0..3) x (top1, top2)
        int p = tid >> 2, c4 = tid & 3;
        int nn = blockIdx.x * 64 + p;
        int2 c2 = pk2[(size_t)c4 * N_ + nn];
        u64 pkd = 0;
#pragma unroll
        for (int t = 0; t < 2; t++) {
            int raw = t ? c2.y : c2.x;
            int k = 8191 - (raw & 0x1fff);
            k = k < 0 ? 0 : (k > K_ - 1 ? K_ - 1 : k);
            float s = rescore(emb, k, zbuf + p * E_);
            u64 pk = ((u64)ford(s) << 32) | (unsigned)(K_ - 1 - k);  // ties -> lowest idx
            pkd = pkd > pk ? pkd : pk;
        }
        u64 o = __shfl_xor(pkd, 1, 64); pkd = pkd > o ? pkd : o;
        o = __shfl_xor(pkd, 2, 64);     pkd = pkd > o ? pkd : o;
        if (c4 == 0) {
            int bi = K_ - 1 - (int)(unsigned)(pkd & 0xffffffffu);
            idxs_s[p] = bi;
            out_idx[nn] = (float)bi;
        }
    }
    __syncthreads();

    int lp = tid & 63, eg = tid >> 6;     // eg 0..3, 8 e's each
    int n  = blockIdx.x * 64 + lp;
    int b  = n >> 12, hw = n & (HW_ - 1);
    int idx = idxs_s[lp];
    const float* er = emb + (size_t)idx * E_ + eg * 8;
    float* o = out_zq + (size_t)b * E_ * HW_ + (size_t)(eg * 8) * HW_ + hw;

    float sq = 0.f;
#pragma unroll
    for (int j = 0; j < 8; j++) {
        float zv = zbuf[lp * E_ + eg * 8 + j];
        float qf = er[j];
        float d = qf - zv;
        sq += d * d;
        o[(size_t)j * HW_] = qf;
    }

#pragma unroll
    for (int off = 32; off > 0; off >>= 1) sq += __shfl_down(sq, off);
    int lane = tid & 63, wid = tid >> 6;
    if (lane == 0) red[wid] = sq;
    __syncthreads();
    if (tid == 0) qpart[blockIdx.x] = red[0] + red[1] + red[2] + red[3];
}

// ---------------- K3: segment-sum + full EMA/division/qloss epilogue ----------------
// grid K/KSEG = 256 blocks; block owns codes [kbase, kbase+KSEG).
// Ballot-compaction scan: all 64 lanes test 64 pixels; matches are processed
// cooperatively (32 lanes load the contiguous 128B z-row + conflict-free LDS atomics)
// instead of a 1-active-lane divergent body.
__global__ __launch_bounds__(256) void k_dwfinal(const float* __restrict__ zws,
                                                 const float* __restrict__ idxf,
                                                 const float* __restrict__ cs,
                                                 const float* __restrict__ ew,
                                                 const float* __restrict__ part_cs,
                                                 const float* __restrict__ qpart,
                                                 float* __restrict__ out_nw,
                                                 float* __restrict__ out_nemb,
                                                 float* __restrict__ out_ncs,
                                                 float* __restrict__ out_ql) {
    __shared__ float acc[KSEG * E_];   // 4 KB
    __shared__ int   cnt_s[KSEG];
    __shared__ float nsum_s;
    int tid = threadIdx.x;
    int lane = tid & 63;
    int w    = tid >> 6;
    int kbase = blockIdx.x * KSEG;

#pragma unroll
    for (int i = 0; i < KSEG * E_ / 256; i++) acc[tid + i * 256] = 0.f;
    if (tid < KSEG) cnt_s[tid] = 0;
    __syncthreads();

    // each wave scans N/4 pixels in 64-wide chunks
    int base = w * (N_ / 4);
    for (int it = 0; it < (N_ / 4) / 64; ++it) {    // 128 iterations
        int nbase = base + it * 64;
        int ii = (int)idxf[nbase + lane];
        unsigned d = (unsigned)(ii - kbase);
        u64 m = __ballot(d < (unsigned)KSEG);
        while (m) {
            int src = (int)__builtin_ctzll(m);
            m &= m - 1;
            int dl = __shfl((int)d, src, 64);       // broadcast matched code offset
            int nn = nbase + src;                   // wave-uniform pixel id
            if (lane < E_) {
                float zv = zws[(size_t)nn * E_ + lane];   // 128B contiguous
                atomicAdd(acc + dl * E_ + lane, zv);      // banks 0..31, conflict-free
            } else if (lane == E_) {
                atomicAdd(cnt_s + dl, 1);
            }
        }
    }
    __syncthreads();

    // nsum = DECAY*sum(cs_in) + OMD*N   (sum(counts) == N exactly)
    if (tid < 64) {
        float s = part_cs[tid] + part_cs[tid + 64];
#pragma unroll
        for (int off = 32; off > 0; off >>= 1) s += __shfl_down(s, off);
        if (tid == 0) nsum_s = DECAY_ * s + OMD_ * (float)N_;
    }
    __syncthreads();
    float nsum = nsum_s;

#pragma unroll
    for (int i = 0; i < 4; i++) {
        int local = tid + i * 256;        // 0..1023
        int kl = local >> 5, c = local & 31;
        int k = kbase + kl;
        float v = DECAY_ * ew[(size_t)k * E_ + c] + OMD_ * acc[local];
        out_nw[(size_t)k * E_ + c] = v;
        float csk = DECAY_ * cs[k] + OMD_ * (float)cnt_s[kl];
        float denom = (csk + EPS_) / (nsum + (float)K_ * EPS_) * nsum;
        out_nemb[(size_t)k * E_ + c] = v / denom;
        if (c == 0) out_ncs[k] = csk;
    }

    if (blockIdx.x == 0 && tid < 64) {
        float s = 0.f;
#pragma unroll
        for (int i = 0; i < 8; i++) s += qpart[tid + i * 64];
#pragma unroll
        for (int off = 32; off > 0; off >>= 1) s += __shfl_down(s, off);
        if (tid == 0) out_ql[0] = BETA_ * s / (float)(B_ * E_ * HW_);
    }
}

extern "C" void kernel_launch(void* const* d_in, const int* in_sizes, int n_in,
                              void* d_out, int out_size, void* d_ws, size_t ws_size,
                              hipStream_t stream) {
    const float* x   = (const float*)d_in[0];
    const float* Wq  = (const float*)d_in[1];
    const float* bq  = (const float*)d_in[2];
    const float* emb = (const float*)d_in[3];
    const float* cs  = (const float*)d_in[4];
    const float* ew  = (const float*)d_in[5];
    float* out = (float*)d_out;
    float* ws  = (float*)d_ws;

    // 4 dispatches total; no memset (all ws words written before read).
    k_pre<<<128 + N_ / 64, 256, 0, stream>>>(emb, cs,
        (uint4*)(ws + WS_EH), (uint4*)(ws + WS_EM), ws + WS_PCS,
        x, Wq, bq, ws + WS_Z);
    k_score_mfma<<<dim3(N_ / PIX, NCHUNK), 512, 0, stream>>>(ws + WS_Z,
        (const char*)(ws + WS_EH), (const char*)(ws + WS_EM),
        (int2*)(ws + WS_PACK));
    k_scatter<<<N_ / 64, 256, 0, stream>>>(ws + WS_Z,
        (const int2*)(ws + WS_PACK), emb,
        out + O_ZQ, out + O_IDX, ws + WS_QP);
    k_dwfinal<<<K_ / KSEG, 256, 0, stream>>>(ws + WS_Z, out + O_IDX, cs, ew,
                                             ws + WS_PCS, ws + WS_QP,
                                             out + O_NW, out + O_NEMB,
                                             out + O_NCS, out + O_QL);
}

// Round 7
// 197.507 us; speedup vs baseline: 1.0676x; 1.0676x over previous
//
#include <hip/hip_runtime.h>

#define B_ 8
#define C_ 256
#define HW_ 4096
#define E_ 32
#define K_ 8192
#define N_ 32768          // B*H*W
#define NCHUNK 4
#define KC_ (K_ / NCHUNK) // 2048
#define NSTAGE (KC_ / 128)   // 16
#define KSEG 32              // codes per k_dwfinal block
#define PIX 128              // pixels per k_score block

#define DECAY_ 0.99f
#define OMD_   0.01f
#define EPS_   1e-5f
#define BETA_  0.25f

// ---- output layout (fp32 elements, concatenated in reference return order) ----
#define O_ZQ   0          // [B,E,H,W] 1048576
#define O_IDX  1048576    // [B,H,W]   32768
#define O_QL   1081344    // scalar    1
#define O_NEMB 1081345    // [K,E]     262144
#define O_NCS  1343489    // [K]       8192
#define O_NW   1351681    // [K,E]     262144

// ---- workspace layout (float offsets); high-water 1573504 floats = 6.3 MB ----
// eh/em PRE-SWIZZLED to MFMA-frag order: uint4 chunk (tile t, quad q, c15) at t*64+q*16+c15.
#define WS_EH   0u        // K*E bf16 hi   [0,       131072)
#define WS_EM   131072u   // K*E bf16 lo   [131072,  262144)
#define WS_Z    262144u   // N*E fp32 z    [262144, 1310720)
#define WS_PACK 1310720u  // 4 chunks x N int2 (top1,top2) [1310720, 1572864)
#define WS_PCS  1572864u  // 128 per-block partial sums of cs_in
#define WS_QP   1572992u  // 512 per-block qloss partials
// NO memset needed: every ws word consumed is written first by a prior kernel.

typedef float f32x4 __attribute__((ext_vector_type(4)));
typedef short s16x8 __attribute__((ext_vector_type(8)));
typedef unsigned long long u64;

__device__ __forceinline__ unsigned short f2bf(float f) {
    unsigned u = __float_as_uint(f);
    u = u + 0x7fffu + ((u >> 16) & 1u);
    return (unsigned short)(u >> 16);
}
__device__ __forceinline__ float bf2f(unsigned short h) {
    return __uint_as_float(((unsigned)h) << 16);
}
__device__ __forceinline__ unsigned ford(float f) {
    unsigned u = __float_as_uint(f);
    return (u & 0x80000000u) ? ~u : (u | 0x80000000u);
}
__device__ __forceinline__ int imax(int a, int b) { return a > b ? a : b; }
__device__ __forceinline__ int imin(int a, int b) { return a < b ? a : b; }

__device__ __forceinline__ void gload_lds16(const void* g, void* l) {
    __builtin_amdgcn_global_load_lds(
        (const __attribute__((address_space(1))) unsigned int*)g,
        (__attribute__((address_space(3))) unsigned int*)l, 16, 0, 0);
}

// ---------------- K0: fused {norm_split + cs-partials} || {z = x@WqT + bq} ----------------
// blocks [0,128): codebook normalize/split (4 thr/row) + per-block sum(cs_in) partial.
// blocks [128,384): z for 128 pixels each; 2 pixels x 8 e's per thread
// (halves the wave-uniform wqt broadcast LDS reads per FMA vs 1 pixel/thread).
__global__ __launch_bounds__(256) void k_pre(const float* __restrict__ emb,
                                             const float* __restrict__ cs,
                                             uint4* __restrict__ eh16,
                                             uint4* __restrict__ em16,
                                             float* __restrict__ part_cs,
                                             const float* __restrict__ x,
                                             const float* __restrict__ Wq,
                                             const float* __restrict__ bq,
                                             float* __restrict__ zout) {
    __shared__ float wqt[C_ * E_];   // 32 KB, used by z branch only
    int tid = threadIdx.x;

    if (blockIdx.x < 128) {
        // ---- norm_split branch ----
        int t4 = blockIdx.x * 256 + tid;           // 0..32767
        int k = t4 >> 2, q = t4 & 3;               // row, quad (8 elements)
        const float4* r = (const float4*)(emb + (size_t)k * E_ + q * 8);
        float4 u0 = r[0], u1 = r[1];
        float ss = u0.x*u0.x + u0.y*u0.y + u0.z*u0.z + u0.w*u0.w
                 + u1.x*u1.x + u1.y*u1.y + u1.z*u1.z + u1.w*u1.w;
        ss += __shfl_xor(ss, 1, 64);
        ss += __shfl_xor(ss, 2, 64);               // full-row ||.||^2 in all 4 lanes
        float inv = 1.0f / fmaxf(sqrtf(ss), 1e-12f);

        float v[8] = {u0.x, u0.y, u0.z, u0.w, u1.x, u1.y, u1.z, u1.w};
        unsigned short h1a[8], h2a[8];
#pragma unroll
        for (int e = 0; e < 8; e++) {
            float en = v[e] * inv;
            unsigned short h1 = f2bf(en);
            float r1 = en - bf2f(h1);
            h1a[e] = h1; h2a[e] = f2bf(r1);
        }
        int t = k >> 4, c15 = k & 15;
        eh16[t * 64 + q * 16 + c15] = ((uint4*)h1a)[0];
        em16[t * 64 + q * 16 + c15] = ((uint4*)h2a)[0];

        // per-block partial of sum(cs_in): rows [blockIdx*64, +64)
        if (tid < 64) {
            float cv = cs[blockIdx.x * 64 + tid];
#pragma unroll
            for (int off = 32; off > 0; off >>= 1) cv += __shfl_down(cv, off);
            if (tid == 0) part_cs[blockIdx.x] = cv;
        }
        return;
    }

    // ---- z branch: 128 pixels, thread owns pixels (lp, lp+64) x 8 e's ----
    int zb = blockIdx.x - 128;
#pragma unroll
    for (int i = 0; i < 32; i++) {
        int g = i * 256 + tid;        // g = e*256 + c  (Wq is [E,C])
        int e = g >> 8;
        int c = g & 255;
        wqt[c * E_ + e] = Wq[g];
    }
    __syncthreads();
    int lp = tid & 63, eg = tid >> 6;
    int n0 = zb * 128 + lp;           // pixel A; pixel B = n0 + 64 (same b: 4096%128==0)
    int b  = n0 >> 12, hw = n0 & (HW_ - 1);
    const float* xp = x + (size_t)b * C_ * HW_ + hw;
    float a[16];
#pragma unroll
    for (int j = 0; j < 16; j++) a[j] = 0.f;
#pragma unroll 4
    for (int c = 0; c < C_; c++) {
        float xa = xp[(size_t)c * HW_];
        float xb = xp[(size_t)c * HW_ + 64];
        const float4* wr = (const float4*)(wqt + c * E_ + eg * 8);
        float4 w0 = wr[0], w1 = wr[1];
        a[0]  += xa * w0.x; a[1]  += xa * w0.y; a[2]  += xa * w0.z; a[3]  += xa * w0.w;
        a[4]  += xa * w1.x; a[5]  += xa * w1.y; a[6]  += xa * w1.z; a[7]  += xa * w1.w;
        a[8]  += xb * w0.x; a[9]  += xb * w0.y; a[10] += xb * w0.z; a[11] += xb * w0.w;
        a[12] += xb * w1.x; a[13] += xb * w1.y; a[14] += xb * w1.z; a[15] += xb * w1.w;
    }
    float bqv[8];
#pragma unroll
    for (int j = 0; j < 8; j++) bqv[j] = bq[eg * 8 + j];
    float4* zgA = (float4*)(zout + (size_t)n0 * E_ + eg * 8);
    float4* zgB = (float4*)(zout + (size_t)(n0 + 64) * E_ + eg * 8);
    zgA[0] = make_float4(a[0]+bqv[0],  a[1]+bqv[1],  a[2]+bqv[2],  a[3]+bqv[3]);
    zgA[1] = make_float4(a[4]+bqv[4],  a[5]+bqv[5],  a[6]+bqv[6],  a[7]+bqv[7]);
    zgB[0] = make_float4(a[8]+bqv[0],  a[9]+bqv[1],  a[10]+bqv[2], a[11]+bqv[3]);
    zgB[1] = make_float4(a[12]+bqv[4], a[13]+bqv[5], a[14]+bqv[6], a[15]+bqv[7]);
}

// ---------------- K1: MFMA score + int-packed per-pixel chunk-local top-2 ----------------
// grid (N/128, NCHUNK), 512 thr (8 waves), 128 pixels, quarter codebook per block.
// NO min-waves clause: round-3 showed __launch_bounds__(512,8) squeezes VGPR 44->32
// and spills to scratch (WRITE_SIZE 1MB->303MB). Plain (512) keeps 44 VGPR.
// LDS: [0,16384) buf0, [16384,32768) buf1 (stage: 8KB hi + 8KB lo).
__global__ __launch_bounds__(512) void k_score_mfma(const float* __restrict__ zws,
                                                    const char* __restrict__ ehb,
                                                    const char* __restrict__ emb_b,
                                                    int2* __restrict__ pk2) {
    __shared__ __align__(16) char smem[32768];

    int tid  = threadIdx.x;
    int lane = tid & 63;
    int w    = tid >> 6;          // 0..7
    int chunk = blockIdx.y;

    // ---- A fragments from cached z: z * 2^27 (exact), 2-way bf16 split.
    //      A[m=lane&15][k=(lane>>4)*8+j] ----
    s16x8 a1, a2;
    {
        int ploc = w * 16 + (lane & 15);          // 0..127
        int n0   = blockIdx.x * PIX + ploc;
        int e0   = (lane >> 4) * 8;
        const float4* zp = (const float4*)(zws + (size_t)n0 * E_ + e0);
        float4 z0 = zp[0], z1 = zp[1];
        float zz[8] = {z0.x, z0.y, z0.z, z0.w, z1.x, z1.y, z1.z, z1.w};
#pragma unroll
        for (int j = 0; j < 8; j++) {
            float zv = zz[j] * 134217728.0f;  // 2^27
            unsigned short h1 = f2bf(zv);
            float r1 = zv - bf2f(h1);
            a1[j] = (short)h1; a2[j] = (short)f2bf(r1);
        }
    }

    // staging sources (pre-swizzled planes are stage-linear); 512 thr x 2 = 1024 chunks
    const char* srcp[2];
#pragma unroll
    for (int i = 0; i < 2; i++) {
        int d = i * 512 + tid;
        int pl = d >> 9, dd = d & 511;
        srcp[i] = (pl ? emb_b : ehb) + (size_t)chunk * (KC_ * 64) + dd * 16;
    }

    // prologue: stage 0 -> buf0
#pragma unroll
    for (int i = 0; i < 2; i++)
        gload_lds16(srcp[i], smem + (i * 512 + tid) * 16);
    __syncthreads();

    int rbase = 8191 - chunk * KC_ - (lane & 15);
    int bq1[4], bq2[4];
#pragma unroll
    for (int j = 0; j < 4; j++) { bq1[j] = (int)0x80000000; bq2[j] = (int)0x80000000; }
    f32x4 zero4 = {0.f, 0.f, 0.f, 0.f};

    for (int st = 0; st < NSTAGE; st++) {
        if (st + 1 < NSTAGE) {
            char* dst = smem + ((st + 1) & 1) * 16384;
#pragma unroll
            for (int i = 0; i < 2; i++)
                gload_lds16(srcp[i] + (size_t)(st + 1) * 8192, dst + (i * 512 + tid) * 16);
        }
        const char* cur = smem + (st & 1) * 16384;
        int rst = rbase - st * 128;

#pragma unroll
        for (int g = 0; g < 2; g++) {
            int ct = g * 4;
            s16x8 b1[4], b2[4];
#pragma unroll
            for (int q = 0; q < 4; q++) {
                b1[q] = ((const s16x8*)(cur +        (ct + q) * 1024))[lane];
                b2[q] = ((const s16x8*)(cur + 8192 + (ct + q) * 1024))[lane];
            }
            f32x4 acc[4];
#pragma unroll
            for (int q = 0; q < 4; q++)
                acc[q] = __builtin_amdgcn_mfma_f32_16x16x32_bf16(a1, b1[q], zero4, 0, 0, 0);
#pragma unroll
            for (int q = 0; q < 4; q++)
                acc[q] = __builtin_amdgcn_mfma_f32_16x16x32_bf16(a1, b2[q], acc[q], 0, 0, 0);
#pragma unroll
            for (int q = 0; q < 4; q++)
                acc[q] = __builtin_amdgcn_mfma_f32_16x16x32_bf16(a2, b1[q], acc[q], 0, 0, 0);
            int r0 = rst - ct * 16;
            // tournament over 4 tiles; only the group winner enters the running top-2.
            // (safe: a dropped group loser matters only on a packed-key quantization
            //  tie — P ~ 1e-4/run — and the exact rescore of 8 candidates covers ties.)
#pragma unroll
            for (int j = 0; j < 4; j++) {
                int v0 = ((int)acc[0][j] & (int)0xFFFFE000) | r0;
                int v1 = ((int)acc[1][j] & (int)0xFFFFE000) | (r0 - 16);
                int v2 = ((int)acc[2][j] & (int)0xFFFFE000) | (r0 - 32);
                int v3 = ((int)acc[3][j] & (int)0xFFFFE000) | (r0 - 48);
                int hi = imax(imax(v0, v1), imax(v2, v3));
                int m  = imin(bq1[j], hi);
                bq1[j] = imax(bq1[j], hi);
                bq2[j] = imax(bq2[j], m);
            }
        }
        __syncthreads();
    }

    // butterfly top-2 merge across 16-lane code groups
#pragma unroll
    for (int off = 1; off < 16; off <<= 1) {
#pragma unroll
        for (int j = 0; j < 4; j++) {
            int o1 = __shfl_xor(bq1[j], off, 64);
            int o2 = __shfl_xor(bq2[j], off, 64);
            int m  = imin(bq1[j], o1);
            bq1[j] = imax(bq1[j], o1);
            bq2[j] = imax(imax(bq2[j], o2), m);
        }
    }
    if ((lane & 15) == 0) {
        int rowbase = blockIdx.x * PIX + w * 16 + (lane >> 4) * 4;
#pragma unroll
        for (int j = 0; j < 4; j++)
            pk2[(size_t)chunk * N_ + rowbase + j] = make_int2(bq1[j], bq2[j]);
    }
}

// exact rescore of one candidate code against z[32]
__device__ __forceinline__ float rescore(const float* __restrict__ emb, int k,
                                         const float* zrow) {
    const float4* r = (const float4*)(emb + (size_t)k * E_);
    float4 v[8];
    float ss = 0.f;
#pragma unroll
    for (int i = 0; i < 8; i++) {
        v[i] = r[i];
        ss += v[i].x * v[i].x + v[i].y * v[i].y + v[i].z * v[i].z + v[i].w * v[i].w;
    }
    float inv = 1.0f / fmaxf(sqrtf(ss), 1e-12f);
    const float4* zp = (const float4*)zrow;
    float sx = 0.f, sy = 0.f, sz = 0.f, sw = 0.f;
#pragma unroll
    for (int i = 0; i < 8; i++) {
        float4 e4 = make_float4(v[i].x * inv, v[i].y * inv, v[i].z * inv, v[i].w * inv);
        float4 zr = zp[i];
        sx += zr.x * e4.x; sy += zr.y * e4.y;
        sz += zr.z * e4.z; sw += zr.w * e4.w;
    }
    return (sx + sy) + (sz + sw);
}

// ---------------- K2: load cached z, rescore 8 candidates, gather + zq/idx/qloss-partial ----------------
// 256 threads, 64 pixels. 4 threads/pixel, each rescores its chunk's (top1, top2).
__global__ __launch_bounds__(256) void k_scatter(const float* __restrict__ zws,
                                                 const int2* __restrict__ pk2,
                                                 const float* __restrict__ emb,
                                                 float* __restrict__ out_zq,
                                                 float* __restrict__ out_idx,
                                                 float* __restrict__ qpart) {
    __shared__ float zbuf[64 * E_];    // 8 KB
    __shared__ int   idxs_s[64];
    __shared__ float red[4];
    int tid = threadIdx.x;

    // coalesced z load: 2048 floats = 512 float4
    const float4* zsrc = (const float4*)(zws + (size_t)blockIdx.x * 64 * E_);
    float4* zdst = (float4*)zbuf;
    zdst[tid]       = zsrc[tid];
    zdst[tid + 256] = zsrc[tid + 256];
    __syncthreads();

    {   // 8 candidates per pixel: (chunk 0..3) x (top1, top2)
        int p = tid >> 2, c4 = tid & 3;
        int nn = blockIdx.x * 64 + p;
        int2 c2 = pk2[(size_t)c4 * N_ + nn];
        u64 pkd = 0;
#pragma unroll
        for (int t = 0; t < 2; t++) {
            int raw = t ? c2.y : c2.x;
            int k = 8191 - (raw & 0x1fff);
            k = k < 0 ? 0 : (k > K_ - 1 ? K_ - 1 : k);
            float s = rescore(emb, k, zbuf + p * E_);
            u64 pk = ((u64)ford(s) << 32) | (unsigned)(K_ - 1 - k);  // ties -> lowest idx
            pkd = pkd > pk ? pkd : pk;
        }
        u64 o = __shfl_xor(pkd, 1, 64); pkd = pkd > o ? pkd : o;
        o = __shfl_xor(pkd, 2, 64);     pkd = pkd > o ? pkd : o;
        if (c4 == 0) {
            int bi = K_ - 1 - (int)(unsigned)(pkd & 0xffffffffu);
            idxs_s[p] = bi;
            out_idx[nn] = (float)bi;
        }
    }
    __syncthreads();

    int lp = tid & 63, eg = tid >> 6;     // eg 0..3, 8 e's each
    int n  = blockIdx.x * 64 + lp;
    int b  = n >> 12, hw = n & (HW_ - 1);
    int idx = idxs_s[lp];
    const float* er = emb + (size_t)idx * E_ + eg * 8;
    float* o = out_zq + (size_t)b * E_ * HW_ + (size_t)(eg * 8) * HW_ + hw;

    float sq = 0.f;
#pragma unroll
    for (int j = 0; j < 8; j++) {
        float zv = zbuf[lp * E_ + eg * 8 + j];
        float qf = er[j];
        float d = qf - zv;
        sq += d * d;
        o[(size_t)j * HW_] = qf;
    }

#pragma unroll
    for (int off = 32; off > 0; off >>= 1) sq += __shfl_down(sq, off);
    int lane = tid & 63, wid = tid >> 6;
    if (lane == 0) red[wid] = sq;
    __syncthreads();
    if (tid == 0) qpart[blockIdx.x] = red[0] + red[1] + red[2] + red[3];
}

// ---------------- K3: segment-sum + full EMA/division/qloss epilogue ----------------
// grid K/KSEG = 256 blocks; block owns codes [kbase, kbase+KSEG).
// Tile-list compaction: per 2048-pixel tile, 256 threads scan 8 pixels each
// (coalesced float4), push matches into an LDS list, then process the list
// FULLY PARALLEL: thread (m,e) = (tid>>5, tid&31) — 8 z-rows in flight,
// 128B coalesced loads, conflict-free LDS adds. No wave-serial match loop.
__global__ __launch_bounds__(256) void k_dwfinal(const float* __restrict__ zws,
                                                 const float* __restrict__ idxf,
                                                 const float* __restrict__ cs,
                                                 const float* __restrict__ ew,
                                                 const float* __restrict__ part_cs,
                                                 const float* __restrict__ qpart,
                                                 float* __restrict__ out_nw,
                                                 float* __restrict__ out_nemb,
                                                 float* __restrict__ out_ncs,
                                                 float* __restrict__ out_ql) {
    __shared__ float acc[KSEG * E_];   // 4 KB
    __shared__ int   cnt_s[KSEG];
    __shared__ int   plist[2048];      // worst-case one tile fully matching
    __shared__ int   lcnt;
    __shared__ float nsum_s;
    int tid = threadIdx.x;
    int kbase = blockIdx.x * KSEG;

#pragma unroll
    for (int i = 0; i < KSEG * E_ / 256; i++) acc[tid + i * 256] = 0.f;
    if (tid < KSEG) cnt_s[tid] = 0;
    if (tid == 0) lcnt = 0;
    __syncthreads();

    const float4* idx4 = (const float4*)idxf;
    for (int tile = 0; tile < N_ / 2048; ++tile) {   // 16 tiles
        int pbase = tile * 2048 + tid * 8;
        float4 f0 = idx4[tile * 512 + tid * 2];
        float4 f1 = idx4[tile * 512 + tid * 2 + 1];
        float fs[8] = {f0.x, f0.y, f0.z, f0.w, f1.x, f1.y, f1.z, f1.w};
#pragma unroll
        for (int s = 0; s < 8; s++) {
            unsigned d = (unsigned)((int)fs[s] - kbase);
            if (d < (unsigned)KSEG) {
                int pos = atomicAdd(&lcnt, 1);
                plist[pos] = ((pbase + s) << 5) | (int)d;
                atomicAdd(cnt_s + (int)d, 1);
            }
        }
        __syncthreads();
        int cnt = lcnt;
        int e = tid & 31;
        for (int m = tid >> 5; m < cnt; m += 8) {
            int pk = plist[m];
            int nn = pk >> 5;
            float zv = zws[(size_t)nn * E_ + e];        // 128B coalesced per match
            atomicAdd(acc + (pk & 31) * E_ + e, zv);    // banks 0..31, conflict-free
        }
        __syncthreads();
        if (tid == 0) lcnt = 0;
        __syncthreads();
    }

    // nsum = DECAY*sum(cs_in) + OMD*N   (sum(counts) == N exactly)
    if (tid < 64) {
        float s = part_cs[tid] + part_cs[tid + 64];
#pragma unroll
        for (int off = 32; off > 0; off >>= 1) s += __shfl_down(s, off);
        if (tid == 0) nsum_s = DECAY_ * s + OMD_ * (float)N_;
    }
    __syncthreads();
    float nsum = nsum_s;

#pragma unroll
    for (int i = 0; i < 4; i++) {
        int local = tid + i * 256;        // 0..1023
        int kl = local >> 5, c = local & 31;
        int k = kbase + kl;
        float v = DECAY_ * ew[(size_t)k * E_ + c] + OMD_ * acc[local];
        out_nw[(size_t)k * E_ + c] = v;
        float csk = DECAY_ * cs[k] + OMD_ * (float)cnt_s[kl];
        float denom = (csk + EPS_) / (nsum + (float)K_ * EPS_) * nsum;
        out_nemb[(size_t)k * E_ + c] = v / denom;
        if (c == 0) out_ncs[k] = csk;
    }

    if (blockIdx.x == 0 && tid < 64) {
        float s = 0.f;
#pragma unroll
        for (int i = 0; i < 8; i++) s += qpart[tid + i * 64];
#pragma unroll
        for (int off = 32; off > 0; off >>= 1) s += __shfl_down(s, off);
        if (tid == 0) out_ql[0] = BETA_ * s / (float)(B_ * E_ * HW_);
    }
}

extern "C" void kernel_launch(void* const* d_in, const int* in_sizes, int n_in,
                              void* d_out, int out_size, void* d_ws, size_t ws_size,
                              hipStream_t stream) {
    const float* x   = (const float*)d_in[0];
    const float* Wq  = (const float*)d_in[1];
    const float* bq  = (const float*)d_in[2];
    const float* emb = (const float*)d_in[3];
    const float* cs  = (const float*)d_in[4];
    const float* ew  = (const float*)d_in[5];
    float* out = (float*)d_out;
    float* ws  = (float*)d_ws;

    // 4 dispatches total; no memset (all ws words written before read).
    k_pre<<<128 + N_ / 128, 256, 0, stream>>>(emb, cs,
        (uint4*)(ws + WS_EH), (uint4*)(ws + WS_EM), ws + WS_PCS,
        x, Wq, bq, ws + WS_Z);
    k_score_mfma<<<dim3(N_ / PIX, NCHUNK), 512, 0, stream>>>(ws + WS_Z,
        (const char*)(ws + WS_EH), (const char*)(ws + WS_EM),
        (int2*)(ws + WS_PACK));
    k_scatter<<<N_ / 64, 256, 0, stream>>>(ws + WS_Z,
        (const int2*)(ws + WS_PACK), emb,
        out + O_ZQ, out + O_IDX, ws + WS_QP);
    k_dwfinal<<<K_ / KSEG, 256, 0, stream>>>(ws + WS_Z, out + O_IDX, cs, ew,
                                             ws + WS_PCS, ws + WS_QP,
                                             out + O_NW, out + O_NEMB,
                                             out + O_NCS, out + O_QL);
}